// Round 5
// baseline (205.779 us; speedup 1.0000x reference)
//
#include <hip/hip_runtime.h>
#include <hip/hip_bf16.h>
#include <stdint.h>

#define N_ROWS 8192
#define DIM    1024
#define TEMP_INV 10.0f
#define NCHUNK 32
#define BM 256
#define BN 256

// LDS element offsets (unsigned short elems); each region 256 rows x 64 cols
#define A0E 0
#define A1E 16384
#define B0E 32768
#define B1E 49152

typedef __attribute__((ext_vector_type(8))) short bf16x8;
typedef __attribute__((ext_vector_type(4))) float f32x4;

__device__ __forceinline__ void gload_lds16(const void* g, void* l) {
  __builtin_amdgcn_global_load_lds(
      (const __attribute__((address_space(1))) unsigned int*)g,
      (__attribute__((address_space(3))) unsigned int*)l, 16, 0, 0);
}

__device__ __forceinline__ unsigned short f2bf(float x) {
  unsigned int u = __float_as_uint(x);
  unsigned int r = (u + 0x7FFFu + ((u >> 16) & 1u)) >> 16;
  return (unsigned short)r;
}

// -------- Kernel 1: L2-normalize rows, convert to bf16 --------
__global__ void norm_bf16_kernel(const float* __restrict__ ctx,
                                 const float* __restrict__ gls,
                                 unsigned short* __restrict__ Cn,
                                 unsigned short* __restrict__ Gn) {
  int row = blockIdx.x;
  const float* src;
  unsigned short* dst;
  if (row < N_ROWS) { src = ctx + (size_t)row * DIM; dst = Cn + (size_t)row * DIM; }
  else { src = gls + (size_t)(row - N_ROWS) * DIM; dst = Gn + (size_t)(row - N_ROWS) * DIM; }
  int t = threadIdx.x;
  float4 v = ((const float4*)src)[t];
  float ss = v.x*v.x + v.y*v.y + v.z*v.z + v.w*v.w;
  #pragma unroll
  for (int m = 1; m < 64; m <<= 1) ss += __shfl_xor(ss, m);
  __shared__ float wss[4];
  if ((t & 63) == 0) wss[t >> 6] = ss;
  __syncthreads();
  float tot = wss[0] + wss[1] + wss[2] + wss[3];
  float inv = 1.0f / fmaxf(sqrtf(tot), 1e-12f);
  unsigned short o0 = f2bf(v.x * inv);
  unsigned short o1 = f2bf(v.y * inv);
  unsigned short o2 = f2bf(v.z * inv);
  unsigned short o3 = f2bf(v.w * inv);
  unsigned long long pack = (unsigned long long)o0 | ((unsigned long long)o1 << 16) |
                            ((unsigned long long)o2 << 32) | ((unsigned long long)o3 << 48);
  *(unsigned long long*)(dst + (size_t)t * 4) = pack;
}

// ---- staging: 2 gload_lds per call (rows j=0/1 blocks of 64/32) ----
#define STAGE_A(abase, h, kt) do { \
    gload_lds16(gA + (size_t)((h) * 64) * DIM + (kt) * 64, \
                &lds[(abase) + (h) * 4096 + dAa]); \
    gload_lds16(gA + (size_t)((h) * 64 + 128) * DIM + (kt) * 64, \
                &lds[(abase) + (h) * 4096 + 8192 + dAa]); \
  } while (0)
#define STAGE_B(bbase, h, kt) do { \
    gload_lds16(gB + (size_t)((h) * 32) * DIM + (kt) * 64, \
                &lds[(bbase) + (h) * 2048 + dBb]); \
    gload_lds16(gB + (size_t)((h) * 32 + 128) * DIM + (kt) * 64, \
                &lds[(bbase) + (h) * 2048 + 8192 + dBb]); \
  } while (0)

#define LDSV(off) (*(const bf16x8*)&lds[off])

#define MFMA_CLUSTER(AF, NB, MB) \
    _Pragma("unroll") \
    for (int mi = 0; mi < 4; ++mi) \
      _Pragma("unroll") \
      for (int ni = 0; ni < 2; ++ni) { \
        acc[(MB) + mi][(NB) + ni] = __builtin_amdgcn_mfma_f32_16x16x32_bf16( \
            AF[mi][0], bfr[(NB) + ni][0], acc[(MB) + mi][(NB) + ni], 0, 0, 0); \
        acc[(MB) + mi][(NB) + ni] = __builtin_amdgcn_mfma_f32_16x16x32_bf16( \
            AF[mi][1], bfr[(NB) + ni][1], acc[(MB) + mi][(NB) + ni], 0, 0, 0); \
      }

// One 4-phase window: compute K-tile from (RAE,RBE); stage B(KB)->STBE (ph1,2),
// stage A(KA)->RAE (ph4). vmcnt(4) at window end (4 youngest loads in flight).
#define WINDOW(RAE, RBE, STBE, KB, KA) do { \
    bf16x8 af0[4][2], af1[4][2], bfr[4][2]; \
    /* phase 1: read A(mi0-3) + B(ni0-1); stage B-h0 */ \
    _Pragma("unroll") \
    for (int mi = 0; mi < 4; ++mi) { \
      af0[mi][0] = LDSV((RAE) + ar0 + mi * 1024); \
      af0[mi][1] = LDSV((RAE) + ar1 + mi * 1024); \
    } \
    _Pragma("unroll") \
    for (int ni = 0; ni < 2; ++ni) { \
      bfr[ni][0] = LDSV((RBE) + br0 + ni * 1024); \
      bfr[ni][1] = LDSV((RBE) + br1 + ni * 1024); \
    } \
    STAGE_B(STBE, 0, KB); \
    __builtin_amdgcn_s_barrier(); \
    asm volatile("s_waitcnt lgkmcnt(0)" ::: "memory"); \
    __builtin_amdgcn_sched_barrier(0); \
    __builtin_amdgcn_s_setprio(1); \
    MFMA_CLUSTER(af0, 0, 0) \
    __builtin_amdgcn_s_setprio(0); \
    __builtin_amdgcn_s_barrier(); \
    /* phase 2: read B(ni2-3); stage B-h1 */ \
    _Pragma("unroll") \
    for (int ni = 0; ni < 2; ++ni) { \
      bfr[2 + ni][0] = LDSV((RBE) + br0 + (2 + ni) * 1024); \
      bfr[2 + ni][1] = LDSV((RBE) + br1 + (2 + ni) * 1024); \
    } \
    STAGE_B(STBE, 1, KB); \
    __builtin_amdgcn_s_barrier(); \
    asm volatile("s_waitcnt lgkmcnt(0)" ::: "memory"); \
    __builtin_amdgcn_sched_barrier(0); \
    __builtin_amdgcn_s_setprio(1); \
    MFMA_CLUSTER(af0, 2, 0) \
    __builtin_amdgcn_s_setprio(0); \
    __builtin_amdgcn_s_barrier(); \
    /* phase 3: read A(mi4-7) */ \
    _Pragma("unroll") \
    for (int mi = 0; mi < 4; ++mi) { \
      af1[mi][0] = LDSV((RAE) + ar0 + (4 + mi) * 1024); \
      af1[mi][1] = LDSV((RAE) + ar1 + (4 + mi) * 1024); \
    } \
    __builtin_amdgcn_s_barrier(); \
    asm volatile("s_waitcnt lgkmcnt(0)" ::: "memory"); \
    __builtin_amdgcn_sched_barrier(0); \
    __builtin_amdgcn_s_setprio(1); \
    MFMA_CLUSTER(af1, 0, 4) \
    __builtin_amdgcn_s_setprio(0); \
    __builtin_amdgcn_s_barrier(); \
    /* phase 4: stage A(KA) both halves (A-region fully read by ph3) */ \
    STAGE_A(RAE, 0, KA); \
    STAGE_A(RAE, 1, KA); \
    __builtin_amdgcn_s_barrier(); \
    __builtin_amdgcn_s_setprio(1); \
    MFMA_CLUSTER(af1, 2, 4) \
    __builtin_amdgcn_s_setprio(0); \
    asm volatile("s_waitcnt vmcnt(4)" ::: "memory"); \
    __builtin_amdgcn_s_barrier(); \
  } while (0)

// -------- Kernel 2: 8-phase 256^2 bf16 GEMM + fused exp/masked reductions --------
__global__ __launch_bounds__(512, 2)
void gemm_reduce_kernel(const unsigned short* __restrict__ Cn,
                        const unsigned short* __restrict__ Gn,
                        const int* __restrict__ labels,
                        float* __restrict__ ws_sp,
                        float* __restrict__ ws_sa,
                        float* __restrict__ ws_mx) {
  __shared__ __align__(16) unsigned short lds[65536];   // 128 KiB (2 bufs x (A+B))
  __shared__ float red_sa[4][BM];
  __shared__ float red_sp[4][BM];
  __shared__ float red_mx[4][BM];

  const int tid = threadIdx.x;
  const int lane = tid & 63;
  const int wv = tid >> 6;       // 0..7
  const int wm = wv >> 2;        // 0..1  (128-row half)
  const int wn = wv & 3;         // 0..3  (64-col quarter)
  const int g = lane >> 4;       // 0..3
  const int fr = lane & 15;      // 0..15
  const int row0 = blockIdx.x * BM;
  const int col0 = blockIdx.y * BN;

  // ---- staging constants (linear LDS dest; swizzle pre-applied on global src) ----
  const int srow = lane >> 3;                  // 0..7
  const int scol8 = (lane & 7) ^ srow;         // pre-swizzled 16B slot (8 slots/row)
  const unsigned short* gA = Cn + (size_t)(row0 + (wv << 3) + srow) * DIM + (scol8 << 3);
  const int brow0 = ((wv >> 2) << 6) + ((wv & 3) << 3);  // B chunk row base per wave
  const unsigned short* gB = Gn + (size_t)(col0 + brow0 + srow) * DIM + (scol8 << 3);
  const int dAa = (wv << 9);                   // A dest elem offset (wave-uniform)
  const int dBb = brow0 << 6;                  // B dest elem offset

  // ---- ds_read fragment base addrs (row&7 == fr&7 for all mi/ni) ----
  const int slot0 = g ^ (fr & 7);              // ks=0 (u=g)
  const int slot1 = (4 + g) ^ (fr & 7);        // ks=1 (u=4+g)
  const int ar0 = (wm * 128 + fr) * 64 + (slot0 << 3);
  const int ar1 = (wm * 128 + fr) * 64 + (slot1 << 3);
  const int br0 = (wn * 64 + fr) * 64 + (slot0 << 3);
  const int br1 = (wn * 64 + fr) * 64 + (slot1 << 3);

  f32x4 acc[8][4];
  #pragma unroll
  for (int mi = 0; mi < 8; ++mi)
    #pragma unroll
    for (int ni = 0; ni < 4; ++ni) {
      f32x4 z = {0.f, 0.f, 0.f, 0.f};
      acc[mi][ni] = z;
    }

  // ---- prologue: tile0 full + tile1 A; keep tile1-A (4 loads) in flight ----
  STAGE_A(A0E, 0, 0); STAGE_A(A0E, 1, 0);
  STAGE_B(B0E, 0, 0); STAGE_B(B0E, 1, 0);
  STAGE_A(A1E, 0, 1); STAGE_A(A1E, 1, 1);
  asm volatile("s_waitcnt vmcnt(4)" ::: "memory");
  __builtin_amdgcn_s_barrier();

  for (int i = 0; i < 8; ++i) {
    const int t1 = 2 * i + 1;
    const int t2 = (2 * i + 2) & 15;
    const int t3 = (2 * i + 3) & 15;
    WINDOW(A0E, B0E, B1E, t1, t2);   // compute tile 2i   (buf0); stage B(t1)->buf1, A(t2)->buf0
    WINDOW(A1E, B1E, B0E, t2, t3);   // compute tile 2i+1 (buf1); stage B(t2)->buf0, A(t3)->buf1
  }
  asm volatile("s_waitcnt vmcnt(0)" ::: "memory");  // drain trailing wrap-staging

  // ======== epilogue: exp + masked row reductions ========
  int cgc[4], clc[4];
  #pragma unroll
  for (int ni = 0; ni < 4; ++ni) {
    cgc[ni] = col0 + wn * 64 + ni * 16 + fr;
    clc[ni] = labels[cgc[ni]];
  }
  #pragma unroll
  for (int mi = 0; mi < 8; ++mi) {
    #pragma unroll
    for (int j = 0; j < 4; ++j) {
      const int rgi = row0 + wm * 128 + mi * 16 + g * 4 + j;
      const int rlab = labels[rgi];
      float va = 0.f, vp = 0.f, vm = -__builtin_inff();
      #pragma unroll
      for (int ni = 0; ni < 4; ++ni) {
        float s10 = acc[mi][ni][j] * TEMP_INV;
        float e = __expf(s10);
        bool offd = (rgi != cgc[ni]);
        float ea = offd ? e : 0.f;
        va += ea;
        vp += (rlab == clc[ni]) ? ea : 0.f;
        vm = offd ? fmaxf(vm, s10) : vm;
      }
      #pragma unroll
      for (int m = 1; m < 16; m <<= 1) {
        va += __shfl_xor(va, m);
        vp += __shfl_xor(vp, m);
        vm = fmaxf(vm, __shfl_xor(vm, m));
      }
      if (fr == 0) {
        int rl_ = wm * 128 + mi * 16 + g * 4 + j;
        red_sa[wn][rl_] = va;
        red_sp[wn][rl_] = vp;
        red_mx[wn][rl_] = vm;
      }
    }
  }
  __syncthreads();
  if (tid < BM) {
    size_t o = (size_t)blockIdx.y * N_ROWS + row0 + tid;
    ws_sa[o] = (red_sa[0][tid] + red_sa[1][tid]) + (red_sa[2][tid] + red_sa[3][tid]);
    ws_sp[o] = (red_sp[0][tid] + red_sp[1][tid]) + (red_sp[2][tid] + red_sp[3][tid]);
    ws_mx[o] = fmaxf(fmaxf(red_mx[0][tid], red_mx[1][tid]), fmaxf(red_mx[2][tid], red_mx[3][tid]));
  }
}

// -------- Kernel 3: combine chunk partials -> per-row loss --------
__global__ void finalize_rows_kernel(const float* __restrict__ ws_sp,
                                     const float* __restrict__ ws_sa,
                                     const float* __restrict__ ws_mx,
                                     float* __restrict__ ws_loss) {
  int r = blockIdx.x * blockDim.x + threadIdx.x;
  float sp = 0.f, sa = 0.f, mx = -__builtin_inff();
  #pragma unroll
  for (int c = 0; c < NCHUNK; ++c) {
    sp += ws_sp[(size_t)c * N_ROWS + r];
    sa += ws_sa[(size_t)c * N_ROWS + r];
    mx = fmaxf(mx, ws_mx[(size_t)c * N_ROWS + r]);
  }
  float frac = (sp + 1e-8f) / (sa + 1e-8f);
  frac = fminf(fmaxf(frac, 1e-8f), 1.0f);
  float loss = -logf(frac);
  if (sp == 0.0f) loss = -mx;   // no-positives fallback (every exp term > 0)
  ws_loss[r] = loss;
}

// -------- Kernel 4: deterministic mean --------
__global__ void mean_kernel(const float* __restrict__ ws_loss, float* __restrict__ out) {
  int t = threadIdx.x;
  float s = 0.f;
  for (int i = t; i < N_ROWS; i += 256) s += ws_loss[i];
  #pragma unroll
  for (int m = 1; m < 64; m <<= 1) s += __shfl_xor(s, m);
  __shared__ float wsum[4];
  if ((t & 63) == 0) wsum[t >> 6] = s;
  __syncthreads();
  if (t == 0) out[0] = (wsum[0] + wsum[1] + wsum[2] + wsum[3]) * (1.0f / N_ROWS);
}

extern "C" void kernel_launch(void* const* d_in, const int* in_sizes, int n_in,
                              void* d_out, int out_size, void* d_ws, size_t ws_size,
                              hipStream_t stream) {
  const float* ctx = (const float*)d_in[0];
  const float* gls = (const float*)d_in[1];
  const int* labels = (const int*)d_in[2];
  float* out = (float*)d_out;

  char* ws = (char*)d_ws;
  unsigned short* Cn = (unsigned short*)ws;                                  // 16 MiB
  unsigned short* Gn = (unsigned short*)(ws + (size_t)N_ROWS * DIM * 2);     // 16 MiB
  float* ws_sp = (float*)(ws + (size_t)2 * N_ROWS * DIM * 2);
  float* ws_sa = ws_sp + (size_t)NCHUNK * N_ROWS;
  float* ws_mx = ws_sa + (size_t)NCHUNK * N_ROWS;
  float* ws_loss = ws_mx + (size_t)NCHUNK * N_ROWS;

  hipLaunchKernelGGL(norm_bf16_kernel, dim3(2 * N_ROWS), dim3(256), 0, stream,
                     ctx, gls, Cn, Gn);
  hipLaunchKernelGGL(gemm_reduce_kernel, dim3(N_ROWS / BM, N_ROWS / BN), dim3(512), 0, stream,
                     Cn, Gn, labels, ws_sp, ws_sa, ws_mx);
  hipLaunchKernelGGL(finalize_rows_kernel, dim3(N_ROWS / 256), dim3(256), 0, stream,
                     ws_sp, ws_sa, ws_mx, ws_loss);
  hipLaunchKernelGGL(mean_kernel, dim3(1), dim3(256), 0, stream, ws_loss, out);
}